// Round 5
// baseline (1095.695 us; speedup 1.0000x reference)
//
#include <hip/hip_runtime.h>

#define NDRUG 20000
#define NTGT  20000
#define NN    40000
#define NE    500000
#define DDIM  128
#define CAP   96

typedef __attribute__((ext_vector_type(4))) float f32x4;
typedef __attribute__((ext_vector_type(8))) short s16x8;

__device__ inline unsigned short bf_rn(float x) {
  unsigned u = __float_as_uint(x);
  return (unsigned short)((u + 0x7FFFu + ((u >> 16) & 1u)) >> 16);
}
__device__ inline float bf_f(unsigned short h) {
  return __uint_as_float(((unsigned)h) << 16);
}
// fp32 -> bf16 hi (RTN) + lo (truncated residual); hi+lo ~ 2^-17 rel error
__device__ __forceinline__ void split1(float x, short& h, short& l) {
  const unsigned u = __float_as_uint(x);
  const unsigned hu = (u + 0x7FFFu + ((u >> 16) & 1u)) & 0xFFFF0000u;
  h = (short)(hu >> 16);
  l = (short)(__float_as_uint(x - __uint_as_float(hu)) >> 16);
}

// ------- weight prep: W [K][128] fp32 -> Wt_hi/Wt_lo [128][K] bf16; grid.y batches -------
__global__ void prep_w(const float* __restrict__ W, short* __restrict__ hi,
                       short* __restrict__ lo, int K) {
  const size_t mat = (size_t)blockIdx.y * K * 128;
  const int idx = blockIdx.x * blockDim.x + threadIdx.x;
  if (idx >= K * 128) return;
  const int k = idx >> 7, c = idx & 127;
  const float x = W[mat + idx];
  const unsigned short h = bf_rn(x);
  hi[mat + (size_t)c * K + k] = (short)h;
  lo[mat + (size_t)c * K + k] = (short)bf_rn(x - bf_f(h));
}

// ---------------- LDS-free projection GEMM ----------------
// Both matrices in one launch. BM=64 x BN=64; 4 waves, each wave owns 16 rows x 64 cols.
// A fp32 loaded per-lane from global (disjoint per wave), converted in-register.
// B (pre-split bf16, L2-resident) loaded per-fragment from global. No LDS, no barriers.
// Writes h as bf16 hi/lo planes.
__global__ __launch_bounds__(256)
void gemm_proj(const float* __restrict__ xd, const short* __restrict__ wdh,
               const short* __restrict__ wdl, const float* __restrict__ bd,
               const float* __restrict__ xt, const short* __restrict__ wth,
               const short* __restrict__ wtl, const float* __restrict__ bt,
               short* __restrict__ hh, short* __restrict__ hl) {
  int b = blockIdx.x;
  const float* A; const short* WH; const short* WL; const float* bias;
  int M, K, rowbase;
  if (b < 626) { A = xd; WH = wdh; WL = wdl; bias = bd; M = NDRUG; K = 2048; rowbase = 0; }
  else { b -= 626; A = xt; WH = wth; WL = wtl; bias = bt; M = NTGT; K = 1280; rowbase = NDRUG; }
  const int bm = (b >> 1) * 64;
  const int bn = (b & 1) * 64;
  const int w = threadIdx.x >> 6, lane = threadIdx.x & 63;
  const int lr = lane & 15, kg = lane >> 4;

  int arow = bm + w * 16 + lr; if (arow >= M) arow = M - 1;
  const float* ap = A + (size_t)arow * K + kg * 8;
  const short* wph = WH + (size_t)(bn + lr) * K + kg * 8;
  const short* wpl = WL + (size_t)(bn + lr) * K + kg * 8;
  const size_t kstep = (size_t)16 * K;  // fragment col stride (16 cols)

  f32x4 acc[4] = {};

#pragma unroll 2
  for (int kk = 0; kk < K; kk += 32) {
    const f32x4 av0 = *(const f32x4*)(ap);
    const f32x4 av1 = *(const f32x4*)(ap + 4);
    ap += 32;
    s16x8 ah, al;
#pragma unroll
    for (int j = 0; j < 4; ++j) {
      short h, l;
      split1(av0[j], h, l); ah[j] = h; al[j] = l;
      split1(av1[j], h, l); ah[j + 4] = h; al[j + 4] = l;
    }
    s16x8 bh[4], bl[4];
#pragma unroll
    for (int n = 0; n < 4; ++n) {
      bh[n] = *(const s16x8*)(wph + n * kstep);
      bl[n] = *(const s16x8*)(wpl + n * kstep);
    }
    wph += 32; wpl += 32;
#pragma unroll
    for (int n = 0; n < 4; ++n) {
      acc[n] = __builtin_amdgcn_mfma_f32_16x16x32_bf16(ah, bh[n], acc[n], 0, 0, 0);
      acc[n] = __builtin_amdgcn_mfma_f32_16x16x32_bf16(ah, bl[n], acc[n], 0, 0, 0);
      acc[n] = __builtin_amdgcn_mfma_f32_16x16x32_bf16(al, bh[n], acc[n], 0, 0, 0);
    }
  }

#pragma unroll
  for (int n = 0; n < 4; ++n) {
    const int col = bn + n * 16 + lr;
    const float bv = bias[col];
#pragma unroll
    for (int r = 0; r < 4; ++r) {
      const int row = bm + w * 16 + kg * 4 + r;
      if (row < M) {
        short h, l;
        split1(acc[n][r] + bv, h, l);
        hh[(size_t)(rowbase + row) * DDIM + col] = h;
        hl[(size_t)(rowbase + row) * DDIM + col] = l;
      }
    }
  }
}

// ---------------- LDS-free GAT GEMM + fused s/d ----------------
// A = h hi/lo bf16 planes [NN][128]; 3 relations via grid.y; col-half via blockIdx.x&1.
// hp [NN][384] fp32; s_half/d_half [2 halves][3 rel][NN] (disjoint writes, summed at use).
__global__ __launch_bounds__(256)
void gemm_gat(const short* __restrict__ ahh, const short* __restrict__ ahl,
              const short* __restrict__ WtH3, const short* __restrict__ WtL3,
              const float* __restrict__ asrc3, const float* __restrict__ adst3,
              float* __restrict__ hp, float* __restrict__ s_half,
              float* __restrict__ d_half) {
  const int rel = blockIdx.y;
  const int half = blockIdx.x & 1;
  const int bm = (blockIdx.x >> 1) * 64;
  const int bn = half * 64;
  const short* WH = WtH3 + (size_t)rel * DDIM * DDIM;
  const short* WL = WtL3 + (size_t)rel * DDIM * DDIM;
  const int w = threadIdx.x >> 6, lane = threadIdx.x & 63;
  const int lr = lane & 15, kg = lane >> 4;

  const int arow = bm + w * 16 + lr;
  const short* aph = ahh + (size_t)arow * DDIM + kg * 8;
  const short* apl = ahl + (size_t)arow * DDIM + kg * 8;
  const short* wph = WH + (size_t)(bn + lr) * DDIM + kg * 8;
  const short* wpl = WL + (size_t)(bn + lr) * DDIM + kg * 8;

  f32x4 acc[4] = {};
#pragma unroll
  for (int ks = 0; ks < 4; ++ks) {
    const s16x8 ah = *(const s16x8*)(aph + ks * 32);
    const s16x8 al = *(const s16x8*)(apl + ks * 32);
    s16x8 bh[4], bl[4];
#pragma unroll
    for (int n = 0; n < 4; ++n) {
      bh[n] = *(const s16x8*)(wph + ks * 32 + n * 16 * DDIM);
      bl[n] = *(const s16x8*)(wpl + ks * 32 + n * 16 * DDIM);
    }
#pragma unroll
    for (int n = 0; n < 4; ++n) {
      acc[n] = __builtin_amdgcn_mfma_f32_16x16x32_bf16(ah, bh[n], acc[n], 0, 0, 0);
      acc[n] = __builtin_amdgcn_mfma_f32_16x16x32_bf16(ah, bl[n], acc[n], 0, 0, 0);
      acc[n] = __builtin_amdgcn_mfma_f32_16x16x32_bf16(al, bh[n], acc[n], 0, 0, 0);
    }
  }

  // hp write
#pragma unroll
  for (int n = 0; n < 4; ++n) {
    const int col = rel * 128 + bn + n * 16 + lr;
#pragma unroll
    for (int r = 0; r < 4; ++r) {
      const int row = bm + w * 16 + kg * 4 + r;
      hp[(size_t)row * 384 + col] = acc[n][r];
    }
  }
  // fused s/d partials (this col-half's contribution)
  float asv[4], adv[4];
#pragma unroll
  for (int n = 0; n < 4; ++n) {
    asv[n] = asrc3[rel * DDIM + bn + n * 16 + lr];
    adv[n] = adst3[rel * DDIM + bn + n * 16 + lr];
  }
#pragma unroll
  for (int r = 0; r < 4; ++r) {
    float ps = 0.f, pd = 0.f;
#pragma unroll
    for (int n = 0; n < 4; ++n) { ps += acc[n][r] * asv[n]; pd += acc[n][r] * adv[n]; }
#pragma unroll
    for (int o = 1; o < 16; o <<= 1) { ps += __shfl_xor(ps, o); pd += __shfl_xor(pd, o); }
    if (lr == 0) {
      const int row = bm + w * 16 + kg * 4 + r;
      s_half[(size_t)(half * 3 + rel) * NN + row] = ps;
      d_half[(size_t)(half * 3 + rel) * NN + row] = pd;
    }
  }
}

// ------------- edge bias for BOTH layers, float2 loads -------------
__global__ __launch_bounds__(256)
void edge_bias_kernel(const float* __restrict__ ea, const float* __restrict__ ae0,
                      const float* __restrict__ ae1, float* __restrict__ b0,
                      float* __restrict__ b1) {
  const int wave = threadIdx.x >> 6, lane = threadIdx.x & 63;
  const int e = blockIdx.x * 4 + wave;
  if (e >= NE) return;
  const float2 v = *(const float2*)(ea + (size_t)e * DDIM + (lane << 1));
  float s0 = v.x * ae0[lane << 1] + v.y * ae0[(lane << 1) + 1];
  float s1 = v.x * ae1[lane << 1] + v.y * ae1[(lane << 1) + 1];
#pragma unroll
  for (int o = 32; o; o >>= 1) { s0 += __shfl_xor(s0, o); s1 += __shfl_xor(s1, o); }
  if (lane == 0) { b0[e] = s0; b1[e] = s1; }
}

// ------------- CSR build (3 relations batched) -------------
__global__ void count3(const int* __restrict__ d0, const int* __restrict__ d1,
                       const int* __restrict__ d2, int* __restrict__ counts) {
  const int rel = blockIdx.y;
  const int* dst = rel == 0 ? d0 : (rel == 1 ? d1 : d2);
  int* c = counts + rel * NN;
  for (int e = blockIdx.x * blockDim.x + threadIdx.x; e < NE; e += gridDim.x * blockDim.x)
    atomicAdd(&c[dst[e]], 1);
}

__global__ __launch_bounds__(1024)
void scan3(const int* __restrict__ counts_all, int* __restrict__ offs_all,
           int* __restrict__ cursor_all) {
  const int rel = blockIdx.x;
  const int* counts = counts_all + rel * NN;
  int* offs = offs_all + rel * (NN + 1);
  int* cursor = cursor_all + rel * (NN + 1);
  __shared__ int part[1024];
  const int t = threadIdx.x;
  const int CH = 40;
  const int base = t * CH;
  const int lim = min(base + CH, NN);
  int sum = 0;
  for (int i = base; i < lim; ++i) sum += counts[i];
  part[t] = sum;
  __syncthreads();
  for (int o = 1; o < 1024; o <<= 1) {
    const int v = (t >= o) ? part[t - o] : 0;
    __syncthreads();
    part[t] += v;
    __syncthreads();
  }
  int run = (t == 0) ? 0 : part[t - 1];
  for (int i = base; i < lim; ++i) { offs[i] = run; cursor[i] = run; run += counts[i]; }
  if (t == 1023) offs[NN] = part[1023];
}

__global__ void fill3(const int* __restrict__ s0, const int* __restrict__ d0,
                      const int* __restrict__ s1, const int* __restrict__ d1,
                      const int* __restrict__ s2, const int* __restrict__ d2,
                      int* __restrict__ cursor_all, int* __restrict__ csrc_all,
                      int* __restrict__ ceid0) {
  const int rel = blockIdx.y;
  const int* src = rel == 0 ? s0 : (rel == 1 ? s1 : s2);
  const int* dst = rel == 0 ? d0 : (rel == 1 ? d1 : d2);
  int* cursor = cursor_all + rel * (NN + 1);
  int* csrc = csrc_all + (size_t)rel * NE;
  for (int e = blockIdx.x * blockDim.x + threadIdx.x; e < NE; e += gridDim.x * blockDim.x) {
    const int p = atomicAdd(&cursor[dst[e]], 1);
    csrc[p] = src[e];
    if (rel == 0) ceid0[p] = e;
  }
}

// ------------- softmax-gather core (one wave, one node, one relation) -------------
__device__ __forceinline__ void gat_one(const int* __restrict__ offs,
                                        const int* __restrict__ csrc,
                                        const int* __restrict__ ceid,
                                        const float* __restrict__ ebias,
                                        const float* __restrict__ s0v,
                                        const float* __restrict__ s1v, float dn,
                                        const float* __restrict__ hpr, int node,
                                        float* exbuf, int* srcbuf, int lane,
                                        float& o0, float& o1) {
  const int beg = offs[node];
  int cnt = offs[node + 1] - beg;
  if (cnt > CAP) cnt = CAP;
  if (cnt == 0) return;
  __threadfence_block();
  float m = -1e30f;
  for (int i = lane; i < cnt; i += 64) {
    const int sn = csrc[beg + i];
    float logit = s0v[sn] + s1v[sn] + dn;
    if (ebias) logit += ebias[ceid[beg + i]];
    const float e = logit >= 0.f ? logit : 0.2f * logit;
    exbuf[i] = e;
    srcbuf[i] = sn;
    m = fmaxf(m, e);
  }
#pragma unroll
  for (int o = 32; o; o >>= 1) m = fmaxf(m, __shfl_xor(m, o));
  float ssum = 0.f;
  for (int i = lane; i < cnt; i += 64) {
    const float ex = __expf(exbuf[i] - m);
    exbuf[i] = ex;
    ssum += ex;
  }
#pragma unroll
  for (int o = 32; o; o >>= 1) ssum += __shfl_xor(ssum, o);
  const float inv = 1.f / (ssum + 1e-16f);
  __threadfence_block();
  const int c = lane << 1;
  float n0 = 0.f, n1 = 0.f;
  int i = 0;
  for (; i + 2 <= cnt; i += 2) {
    const float w0 = exbuf[i], w1 = exbuf[i + 1];
    const float2 v0 = *(const float2*)(hpr + (size_t)srcbuf[i] * 384 + c);
    const float2 v1 = *(const float2*)(hpr + (size_t)srcbuf[i + 1] * 384 + c);
    n0 += w0 * v0.x + w1 * v1.x;
    n1 += w0 * v0.y + w1 * v1.y;
  }
  for (; i < cnt; ++i) {
    const float w = exbuf[i];
    const float2 v = *(const float2*)(hpr + (size_t)srcbuf[i] * 384 + c);
    n0 += w * v.x;
    n1 += w * v.y;
  }
  const float v0 = n0 * inv, v1 = n1 * inv;
  o0 += (v0 > 0.f ? v0 : expm1f(v0));
  o1 += (v1 > 0.f ? v1 : expm1f(v1));
}

// ------------- fused aggregation: all 40000 nodes in one launch -------------
// Layer 0 (write_f32=0): write h as bf16 hi/lo planes. Layer 1: fp32 to out.
__global__ __launch_bounds__(256)
void agg_all(const int* __restrict__ offs_all, const int* __restrict__ csrc_all,
             const int* __restrict__ ceid0, const float* __restrict__ ebias,
             const float* __restrict__ s_half, const float* __restrict__ d_half,
             const float* __restrict__ hp, float* __restrict__ outf,
             short* __restrict__ ohh, short* __restrict__ ohl, int write_f32) {
  __shared__ float exbuf[4][CAP];
  __shared__ int   srcbuf[4][CAP];
  const int wave = threadIdx.x >> 6, lane = threadIdx.x & 63;
  const int node = blockIdx.x * 4 + wave;
  float o0 = 0.f, o1 = 0.f;
  if (node < NDRUG) {
    const float dn = d_half[node] + d_half[3 * NN + node];
    gat_one(offs_all, csrc_all, ceid0, ebias, s_half, s_half + 3 * NN, dn,
            hp, node, exbuf[wave], srcbuf[wave], lane, o0, o1);
  } else {
#pragma unroll
    for (int rel = 1; rel <= 2; ++rel) {
      const float dn = d_half[(size_t)rel * NN + node] + d_half[(size_t)(3 + rel) * NN + node];
      gat_one(offs_all + rel * (NN + 1), csrc_all + (size_t)rel * NE, nullptr, nullptr,
              s_half + (size_t)rel * NN, s_half + (size_t)(3 + rel) * NN, dn,
              hp + rel * 128, node, exbuf[wave], srcbuf[wave], lane, o0, o1);
    }
  }
  o0 *= (1.f / 3.f);
  o1 *= (1.f / 3.f);
  const int c = lane << 1;
  if (write_f32) {
    *(float2*)(outf + (size_t)node * DDIM + c) = make_float2(o0, o1);
  } else {
    short h0, l0, h1, l1;
    split1(o0, h0, l0);
    split1(o1, h1, l1);
    *(short2*)(ohh + (size_t)node * DDIM + c) = make_short2(h0, h1);
    *(short2*)(ohl + (size_t)node * DDIM + c) = make_short2(l0, l1);
  }
}

extern "C" void kernel_launch(void* const* d_in, const int* in_sizes, int n_in,
                              void* d_out, int out_size, void* d_ws, size_t ws_size,
                              hipStream_t stream) {
  const float* x_drug    = (const float*)d_in[0];
  const float* x_target  = (const float*)d_in[1];
  const float* W_drug    = (const float*)d_in[2];
  const float* b_drug    = (const float*)d_in[3];
  const float* W_target  = (const float*)d_in[4];
  const float* b_target  = (const float*)d_in[5];
  const float* W_gat     = (const float*)d_in[6];
  const float* a_src     = (const float*)d_in[7];
  const float* a_dst     = (const float*)d_in[8];
  const float* a_edge    = (const float*)d_in[9];
  const float* edge_attr = (const float*)d_in[10];
  const int*   e_dd      = (const int*)d_in[11];
  const int*   e_dt      = (const int*)d_in[12];
  const int*   e_tt      = (const int*)d_in[13];
  float* out = (float*)d_out;

  char* ws = (char*)d_ws;
  size_t off = 0;
  auto alloc = [&](size_t b) -> void* {
    void* p = ws + off;
    off += (b + 255) & ~(size_t)255;
    return p;
  };
  float* hp     = (float*)alloc((size_t)NN * 384 * 4);
  short* hhA    = (short*)alloc((size_t)NN * DDIM * 2);
  short* hlA    = (short*)alloc((size_t)NN * DDIM * 2);
  short* hhB    = (short*)alloc((size_t)NN * DDIM * 2);
  short* hlB    = (short*)alloc((size_t)NN * DDIM * 2);
  float* s_half = (float*)alloc((size_t)6 * NN * 4);
  float* d_half = (float*)alloc((size_t)6 * NN * 4);
  float* bias0  = (float*)alloc((size_t)NE * 4);
  float* bias1  = (float*)alloc((size_t)NE * 4);
  int* counts   = (int*)alloc((size_t)3 * NN * 4);
  int* offs_all = (int*)alloc((size_t)3 * (NN + 1) * 4);
  int* cur_all  = (int*)alloc((size_t)3 * (NN + 1) * 4);
  int* csrc_all = (int*)alloc((size_t)3 * NE * 4);
  int* ceid0    = (int*)alloc((size_t)NE * 4);
  short* wtd_hi = (short*)alloc((size_t)2048 * 128 * 2);
  short* wtd_lo = (short*)alloc((size_t)2048 * 128 * 2);
  short* wtt_hi = (short*)alloc((size_t)1280 * 128 * 2);
  short* wtt_lo = (short*)alloc((size_t)1280 * 128 * 2);
  short* wtg_hi = (short*)alloc((size_t)6 * 128 * 128 * 2);
  short* wtg_lo = (short*)alloc((size_t)6 * 128 * 128 * 2);

  // 0) weight prep (transpose + hi/lo split)
  prep_w<<<dim3((2048 * 128 + 255) / 256, 1), 256, 0, stream>>>(W_drug, wtd_hi, wtd_lo, 2048);
  prep_w<<<dim3((1280 * 128 + 255) / 256, 1), 256, 0, stream>>>(W_target, wtt_hi, wtt_lo, 1280);
  prep_w<<<dim3((128 * 128 + 255) / 256, 6), 256, 0, stream>>>(W_gat, wtg_hi, wtg_lo, 128);

  // 1) projections -> h hi/lo planes (one launch, LDS-free)
  gemm_proj<<<1252, 256, 0, stream>>>(x_drug, wtd_hi, wtd_lo, b_drug,
                                      x_target, wtt_hi, wtt_lo, b_target, hhA, hlA);

  // 2) edge biases for both layers (one 256MB pass)
  edge_bias_kernel<<<NE / 4, 256, 0, stream>>>(edge_attr, a_edge, a_edge + DDIM,
                                               bias0, bias1);
  // 3) CSR build (3 relations, reused by both layers)
  hipMemsetAsync(counts, 0, (size_t)3 * NN * 4, stream);
  count3<<<dim3(170, 3), 256, 0, stream>>>(e_dd + NE, e_dt + NE, e_tt + NE, counts);
  scan3<<<3, 1024, 0, stream>>>(counts, offs_all, cur_all);
  fill3<<<dim3(170, 3), 256, 0, stream>>>(e_dd, e_dd + NE, e_dt, e_dt + NE,
                                          e_tt, e_tt + NE, cur_all, csrc_all, ceid0);

  // 4) two GAT layers
  // layer 0
  gemm_gat<<<dim3(1250, 3), 256, 0, stream>>>(hhA, hlA, wtg_hi, wtg_lo,
                                              a_src, a_dst, hp, s_half, d_half);
  agg_all<<<NN / 4, 256, 0, stream>>>(offs_all, csrc_all, ceid0, bias0,
                                      s_half, d_half, hp, nullptr, hhB, hlB, 0);
  // layer 1
  gemm_gat<<<dim3(1250, 3), 256, 0, stream>>>(hhB, hlB,
                                              wtg_hi + (size_t)3 * DDIM * DDIM,
                                              wtg_lo + (size_t)3 * DDIM * DDIM,
                                              a_src + 3 * DDIM, a_dst + 3 * DDIM,
                                              hp, s_half, d_half);
  agg_all<<<NN / 4, 256, 0, stream>>>(offs_all, csrc_all, ceid0, bias1,
                                      s_half, d_half, hp, out, nullptr, nullptr, 1);
}

// Round 6
// 851.739 us; speedup vs baseline: 1.2864x; 1.2864x over previous
//
#include <hip/hip_runtime.h>

#define NDRUG 20000
#define NTGT  20000
#define NN    40000
#define NE    500000
#define DDIM  128
#define CAP   96

typedef __attribute__((ext_vector_type(4))) float f32x4;
typedef __attribute__((ext_vector_type(8))) short s16x8;
typedef __attribute__((ext_vector_type(4))) short s16x4;

__device__ inline unsigned short bf_rn(float x) {
  unsigned u = __float_as_uint(x);
  return (unsigned short)((u + 0x7FFFu + ((u >> 16) & 1u)) >> 16);
}
__device__ inline float bf_f(unsigned short h) {
  return __uint_as_float(((unsigned)h) << 16);
}
// fp32 -> bf16 hi (RTN) + lo (truncated residual)
__device__ __forceinline__ void split1(float x, short& h, short& l) {
  const unsigned u = __float_as_uint(x);
  const unsigned hu = (u + 0x7FFFu + ((u >> 16) & 1u)) & 0xFFFF0000u;
  h = (short)(hu >> 16);
  l = (short)(__float_as_uint(x - __uint_as_float(hu)) >> 16);
}

// ------- weight prep: W [K][128] fp32 -> Wt_hi/Wt_lo [128][K] bf16; grid.y batches -------
__global__ void prep_w(const float* __restrict__ W, short* __restrict__ hi,
                       short* __restrict__ lo, int K) {
  const size_t mat = (size_t)blockIdx.y * K * 128;
  const int idx = blockIdx.x * blockDim.x + threadIdx.x;
  if (idx >= K * 128) return;
  const int k = idx >> 7, c = idx & 127;
  const float x = W[mat + idx];
  const unsigned short h = bf_rn(x);
  hi[mat + (size_t)c * K + k] = (short)h;
  lo[mat + (size_t)c * K + k] = (short)bf_rn(x - bf_f(h));
}

// ---------------- LDS-staged projection GEMM, BM=32 BN=128 BK=32 ----------------
// Grid: 625 drug + 625 target blocks. 4 waves: (wm,wn) in 2x2, each 16 rows x 64 cols.
// LDS rows padded to 36 shorts (72B): bank-start row*18%32 -> max 2-way (free).
// Output: h as bf16 hi/lo planes.
__global__ __launch_bounds__(256)
void gemm_proj(const float* __restrict__ xd, const short* __restrict__ wdh,
               const short* __restrict__ wdl, const float* __restrict__ bd,
               const float* __restrict__ xt, const short* __restrict__ wth,
               const short* __restrict__ wtl, const float* __restrict__ bt,
               short* __restrict__ hh, short* __restrict__ hl) {
  __shared__ __align__(16) short Ah[32][36], Al[32][36];
  __shared__ __align__(16) short Bh[128][36], Bl[128][36];

  int b = blockIdx.x;
  const float* A; const short* WH; const short* WL; const float* bias;
  int K, rowbase;
  if (b < 625) { A = xd; WH = wdh; WL = wdl; bias = bd; K = 2048; rowbase = 0; }
  else { b -= 625; A = xt; WH = wth; WL = wtl; bias = bt; K = 1280; rowbase = NDRUG; }
  const int bm = b * 32;

  const int t = threadIdx.x;
  const int wave = t >> 6, lane = t & 63;
  const int wm = wave >> 1, wn = wave & 1;
  const int lr = lane & 15, kg = lane >> 4;

  // staging coords
  const int ar = t >> 3, ac = (t & 7) << 2;      // A: 32 rows x 8 groups of 4 fp32
  const int br = t >> 1, bo = (t & 1) << 4;      // B: 128 rows x 2 chunks of 16 shorts

  f32x4 acc[4] = {};

  for (int kk = 0; kk < K; kk += 32) {
    {
      const float4 v = *(const float4*)(A + (size_t)(bm + ar) * K + kk + ac);
      const float xs[4] = {v.x, v.y, v.z, v.w};
      s16x4 h4, l4;
#pragma unroll
      for (int j = 0; j < 4; ++j) { short h, l; split1(xs[j], h, l); h4[j] = h; l4[j] = l; }
      *(s16x4*)&Ah[ar][ac] = h4;
      *(s16x4*)&Al[ar][ac] = l4;
    }
    {
      const size_t boff = (size_t)br * K + kk + bo;
      *(s16x8*)&Bh[br][bo]     = *(const s16x8*)(WH + boff);
      *(s16x8*)&Bh[br][bo + 8] = *(const s16x8*)(WH + boff + 8);
      *(s16x8*)&Bl[br][bo]     = *(const s16x8*)(WL + boff);
      *(s16x8*)&Bl[br][bo + 8] = *(const s16x8*)(WL + boff + 8);
    }
    __syncthreads();

    const s16x8 ah = *(const s16x8*)&Ah[wm * 16 + lr][kg * 8];
    const s16x8 al = *(const s16x8*)&Al[wm * 16 + lr][kg * 8];
    s16x8 bh[4], bl[4];
#pragma unroll
    for (int n = 0; n < 4; ++n) {
      bh[n] = *(const s16x8*)&Bh[wn * 64 + n * 16 + lr][kg * 8];
      bl[n] = *(const s16x8*)&Bl[wn * 64 + n * 16 + lr][kg * 8];
    }
#pragma unroll
    for (int n = 0; n < 4; ++n) {
      acc[n] = __builtin_amdgcn_mfma_f32_16x16x32_bf16(ah, bh[n], acc[n], 0, 0, 0);
      acc[n] = __builtin_amdgcn_mfma_f32_16x16x32_bf16(ah, bl[n], acc[n], 0, 0, 0);
      acc[n] = __builtin_amdgcn_mfma_f32_16x16x32_bf16(al, bh[n], acc[n], 0, 0, 0);
    }
    __syncthreads();
  }

#pragma unroll
  for (int n = 0; n < 4; ++n) {
    const int col = wn * 64 + n * 16 + lr;
    const float bv = bias[col];
#pragma unroll
    for (int r = 0; r < 4; ++r) {
      const int row = rowbase + bm + wm * 16 + kg * 4 + r;
      short h, l;
      split1(acc[n][r] + bv, h, l);
      hh[(size_t)row * DDIM + col] = h;
      hl[(size_t)row * DDIM + col] = l;
    }
  }
}

// ---------------- LDS-staged GAT GEMM (bf16-plane A) + fused s/d ----------------
// BM=32, BN=128 (one relation), K=128. Grid (1250, 3). hp [NN][384] fp32.
__global__ __launch_bounds__(256)
void gemm_gat(const short* __restrict__ ahh, const short* __restrict__ ahl,
              const short* __restrict__ WtH3, const short* __restrict__ WtL3,
              const float* __restrict__ asrc3, const float* __restrict__ adst3,
              float* __restrict__ hp, float* __restrict__ s_all,
              float* __restrict__ d_all) {
  __shared__ __align__(16) short Ah[32][36], Al[32][36];
  __shared__ __align__(16) short Bh[128][36], Bl[128][36];
  __shared__ float sred[2][32], dred[2][32];

  const int rel = blockIdx.y;
  const int bm = blockIdx.x * 32;
  const short* WH = WtH3 + (size_t)rel * DDIM * DDIM;
  const short* WL = WtL3 + (size_t)rel * DDIM * DDIM;

  const int t = threadIdx.x;
  const int wave = t >> 6, lane = t & 63;
  const int wm = wave >> 1, wn = wave & 1;
  const int lr = lane & 15, kg = lane >> 4;

  // staging coords: A 32 rows x 32 cols bf16 x2 planes; 128 threads per plane
  const int ap = t >> 7, ai = t & 127;
  const int aar = ai >> 2, aac = (ai & 3) << 3;  // 32 rows x 4 chunks of 8 shorts
  const int br = t >> 1, bo = (t & 1) << 4;

  f32x4 acc[4] = {};

#pragma unroll
  for (int ks = 0; ks < 4; ++ks) {
    const int kk = ks * 32;
    {
      const short* src = (ap ? ahl : ahh) + (size_t)(bm + aar) * DDIM + kk + aac;
      short* dst = ap ? &Al[aar][aac] : &Ah[aar][aac];
      *(s16x8*)dst = *(const s16x8*)src;
    }
    {
      const size_t boff = (size_t)br * DDIM + kk + bo;
      *(s16x8*)&Bh[br][bo]     = *(const s16x8*)(WH + boff);
      *(s16x8*)&Bh[br][bo + 8] = *(const s16x8*)(WH + boff + 8);
      *(s16x8*)&Bl[br][bo]     = *(const s16x8*)(WL + boff);
      *(s16x8*)&Bl[br][bo + 8] = *(const s16x8*)(WL + boff + 8);
    }
    __syncthreads();

    const s16x8 ah = *(const s16x8*)&Ah[wm * 16 + lr][kg * 8];
    const s16x8 al = *(const s16x8*)&Al[wm * 16 + lr][kg * 8];
    s16x8 bh[4], bl[4];
#pragma unroll
    for (int n = 0; n < 4; ++n) {
      bh[n] = *(const s16x8*)&Bh[wn * 64 + n * 16 + lr][kg * 8];
      bl[n] = *(const s16x8*)&Bl[wn * 64 + n * 16 + lr][kg * 8];
    }
#pragma unroll
    for (int n = 0; n < 4; ++n) {
      acc[n] = __builtin_amdgcn_mfma_f32_16x16x32_bf16(ah, bh[n], acc[n], 0, 0, 0);
      acc[n] = __builtin_amdgcn_mfma_f32_16x16x32_bf16(ah, bl[n], acc[n], 0, 0, 0);
      acc[n] = __builtin_amdgcn_mfma_f32_16x16x32_bf16(al, bh[n], acc[n], 0, 0, 0);
    }
    __syncthreads();
  }

  // hp write
#pragma unroll
  for (int n = 0; n < 4; ++n) {
    const int col = rel * 128 + wn * 64 + n * 16 + lr;
#pragma unroll
    for (int r = 0; r < 4; ++r) {
      const int row = bm + wm * 16 + kg * 4 + r;
      hp[(size_t)row * 384 + col] = acc[n][r];
    }
  }
  // fused s/d: per-row dot with a_src/a_dst, reduced over 16 lanes + 2 wn waves
  float asv[4], adv[4];
#pragma unroll
  for (int n = 0; n < 4; ++n) {
    asv[n] = asrc3[rel * DDIM + wn * 64 + n * 16 + lr];
    adv[n] = adst3[rel * DDIM + wn * 64 + n * 16 + lr];
  }
#pragma unroll
  for (int r = 0; r < 4; ++r) {
    float ps = 0.f, pd = 0.f;
#pragma unroll
    for (int n = 0; n < 4; ++n) { ps += acc[n][r] * asv[n]; pd += acc[n][r] * adv[n]; }
#pragma unroll
    for (int o = 1; o < 16; o <<= 1) { ps += __shfl_xor(ps, o); pd += __shfl_xor(pd, o); }
    if (lr == 0) {
      const int lrow = wm * 16 + kg * 4 + r;
      sred[wn][lrow] = ps;
      dred[wn][lrow] = pd;
    }
  }
  __syncthreads();
  if (t < 32) {
    s_all[(size_t)rel * NN + bm + t] = sred[0][t] + sred[1][t];
    d_all[(size_t)rel * NN + bm + t] = dred[0][t] + dred[1][t];
  }
}

// ------------- edge bias for BOTH layers, float2 loads -------------
__global__ __launch_bounds__(256)
void edge_bias_kernel(const float* __restrict__ ea, const float* __restrict__ ae0,
                      const float* __restrict__ ae1, float* __restrict__ b0,
                      float* __restrict__ b1) {
  const int wave = threadIdx.x >> 6, lane = threadIdx.x & 63;
  const int e = blockIdx.x * 4 + wave;
  if (e >= NE) return;
  const float2 v = *(const float2*)(ea + (size_t)e * DDIM + (lane << 1));
  float s0 = v.x * ae0[lane << 1] + v.y * ae0[(lane << 1) + 1];
  float s1 = v.x * ae1[lane << 1] + v.y * ae1[(lane << 1) + 1];
#pragma unroll
  for (int o = 32; o; o >>= 1) { s0 += __shfl_xor(s0, o); s1 += __shfl_xor(s1, o); }
  if (lane == 0) { b0[e] = s0; b1[e] = s1; }
}

// ------------- CSR build (3 relations batched) -------------
__global__ void count3(const int* __restrict__ d0, const int* __restrict__ d1,
                       const int* __restrict__ d2, int* __restrict__ counts) {
  const int rel = blockIdx.y;
  const int* dst = rel == 0 ? d0 : (rel == 1 ? d1 : d2);
  int* c = counts + rel * NN;
  for (int e = blockIdx.x * blockDim.x + threadIdx.x; e < NE; e += gridDim.x * blockDim.x)
    atomicAdd(&c[dst[e]], 1);
}

__global__ __launch_bounds__(1024)
void scan3(const int* __restrict__ counts_all, int* __restrict__ offs_all,
           int* __restrict__ cursor_all) {
  const int rel = blockIdx.x;
  const int* counts = counts_all + rel * NN;
  int* offs = offs_all + rel * (NN + 1);
  int* cursor = cursor_all + rel * (NN + 1);
  __shared__ int part[1024];
  const int t = threadIdx.x;
  const int CH = 40;
  const int base = t * CH;
  const int lim = min(base + CH, NN);
  int sum = 0;
  for (int i = base; i < lim; ++i) sum += counts[i];
  part[t] = sum;
  __syncthreads();
  for (int o = 1; o < 1024; o <<= 1) {
    const int v = (t >= o) ? part[t - o] : 0;
    __syncthreads();
    part[t] += v;
    __syncthreads();
  }
  int run = (t == 0) ? 0 : part[t - 1];
  for (int i = base; i < lim; ++i) { offs[i] = run; cursor[i] = run; run += counts[i]; }
  if (t == 1023) offs[NN] = part[1023];
}

__global__ void fill3(const int* __restrict__ s0, const int* __restrict__ d0,
                      const int* __restrict__ s1, const int* __restrict__ d1,
                      const int* __restrict__ s2, const int* __restrict__ d2,
                      int* __restrict__ cursor_all, int* __restrict__ csrc_all,
                      int* __restrict__ ceid0) {
  const int rel = blockIdx.y;
  const int* src = rel == 0 ? s0 : (rel == 1 ? s1 : s2);
  const int* dst = rel == 0 ? d0 : (rel == 1 ? d1 : d2);
  int* cursor = cursor_all + rel * (NN + 1);
  int* csrc = csrc_all + (size_t)rel * NE;
  for (int e = blockIdx.x * blockDim.x + threadIdx.x; e < NE; e += gridDim.x * blockDim.x) {
    const int p = atomicAdd(&cursor[dst[e]], 1);
    csrc[p] = src[e];
    if (rel == 0) ceid0[p] = e;
  }
}

// ------------- softmax-gather core (one wave, one node, one relation) -------------
__device__ __forceinline__ void gat_one(const int* __restrict__ offs,
                                        const int* __restrict__ csrc,
                                        const int* __restrict__ ceid,
                                        const float* __restrict__ ebias,
                                        const float* __restrict__ s, float dn,
                                        const float* __restrict__ hpr, int node,
                                        float* exbuf, int* srcbuf, int lane,
                                        float& o0, float& o1) {
  const int beg = offs[node];
  int cnt = offs[node + 1] - beg;
  if (cnt > CAP) cnt = CAP;
  if (cnt == 0) return;
  __threadfence_block();
  float m = -1e30f;
  for (int i = lane; i < cnt; i += 64) {
    const int sn = csrc[beg + i];
    float logit = s[sn] + dn;
    if (ebias) logit += ebias[ceid[beg + i]];
    const float e = logit >= 0.f ? logit : 0.2f * logit;
    exbuf[i] = e;
    srcbuf[i] = sn;
    m = fmaxf(m, e);
  }
#pragma unroll
  for (int o = 32; o; o >>= 1) m = fmaxf(m, __shfl_xor(m, o));
  float ssum = 0.f;
  for (int i = lane; i < cnt; i += 64) {
    const float ex = __expf(exbuf[i] - m);
    exbuf[i] = ex;
    ssum += ex;
  }
#pragma unroll
  for (int o = 32; o; o >>= 1) ssum += __shfl_xor(ssum, o);
  const float inv = 1.f / (ssum + 1e-16f);
  __threadfence_block();
  const int c = lane << 1;
  float n0 = 0.f, n1 = 0.f;
  int i = 0;
  for (; i + 2 <= cnt; i += 2) {
    const float w0 = exbuf[i], w1 = exbuf[i + 1];
    const float2 v0 = *(const float2*)(hpr + (size_t)srcbuf[i] * 384 + c);
    const float2 v1 = *(const float2*)(hpr + (size_t)srcbuf[i + 1] * 384 + c);
    n0 += w0 * v0.x + w1 * v1.x;
    n1 += w0 * v0.y + w1 * v1.y;
  }
  for (; i < cnt; ++i) {
    const float w = exbuf[i];
    const float2 v = *(const float2*)(hpr + (size_t)srcbuf[i] * 384 + c);
    n0 += w * v.x;
    n1 += w * v.y;
  }
  const float v0 = n0 * inv, v1 = n1 * inv;
  o0 += (v0 > 0.f ? v0 : expm1f(v0));
  o1 += (v1 > 0.f ? v1 : expm1f(v1));
}

// ------------- fused aggregation: all 40000 nodes in one launch -------------
__global__ __launch_bounds__(256)
void agg_all(const int* __restrict__ offs_all, const int* __restrict__ csrc_all,
             const int* __restrict__ ceid0, const float* __restrict__ ebias,
             const float* __restrict__ s_all, const float* __restrict__ d_all,
             const float* __restrict__ hp, float* __restrict__ outf,
             short* __restrict__ ohh, short* __restrict__ ohl, int write_f32) {
  __shared__ float exbuf[4][CAP];
  __shared__ int   srcbuf[4][CAP];
  const int wave = threadIdx.x >> 6, lane = threadIdx.x & 63;
  const int node = blockIdx.x * 4 + wave;
  float o0 = 0.f, o1 = 0.f;
  if (node < NDRUG) {
    gat_one(offs_all, csrc_all, ceid0, ebias, s_all, d_all[node],
            hp, node, exbuf[wave], srcbuf[wave], lane, o0, o1);
  } else {
#pragma unroll
    for (int rel = 1; rel <= 2; ++rel) {
      gat_one(offs_all + rel * (NN + 1), csrc_all + (size_t)rel * NE, nullptr, nullptr,
              s_all + (size_t)rel * NN, d_all[(size_t)rel * NN + node],
              hp + rel * 128, node, exbuf[wave], srcbuf[wave], lane, o0, o1);
    }
  }
  o0 *= (1.f / 3.f);
  o1 *= (1.f / 3.f);
  const int c = lane << 1;
  if (write_f32) {
    *(float2*)(outf + (size_t)node * DDIM + c) = make_float2(o0, o1);
  } else {
    short h0, l0, h1, l1;
    split1(o0, h0, l0);
    split1(o1, h1, l1);
    *(short2*)(ohh + (size_t)node * DDIM + c) = make_short2(h0, h1);
    *(short2*)(ohl + (size_t)node * DDIM + c) = make_short2(l0, l1);
  }
}

extern "C" void kernel_launch(void* const* d_in, const int* in_sizes, int n_in,
                              void* d_out, int out_size, void* d_ws, size_t ws_size,
                              hipStream_t stream) {
  const float* x_drug    = (const float*)d_in[0];
  const float* x_target  = (const float*)d_in[1];
  const float* W_drug    = (const float*)d_in[2];
  const float* b_drug    = (const float*)d_in[3];
  const float* W_target  = (const float*)d_in[4];
  const float* b_target  = (const float*)d_in[5];
  const float* W_gat     = (const float*)d_in[6];
  const float* a_src     = (const float*)d_in[7];
  const float* a_dst     = (const float*)d_in[8];
  const float* a_edge    = (const float*)d_in[9];
  const float* edge_attr = (const float*)d_in[10];
  const int*   e_dd      = (const int*)d_in[11];
  const int*   e_dt      = (const int*)d_in[12];
  const int*   e_tt      = (const int*)d_in[13];
  float* out = (float*)d_out;

  char* ws = (char*)d_ws;
  size_t off = 0;
  auto alloc = [&](size_t b) -> void* {
    void* p = ws + off;
    off += (b + 255) & ~(size_t)255;
    return p;
  };
  float* hp     = (float*)alloc((size_t)NN * 384 * 4);
  short* hhA    = (short*)alloc((size_t)NN * DDIM * 2);
  short* hlA    = (short*)alloc((size_t)NN * DDIM * 2);
  short* hhB    = (short*)alloc((size_t)NN * DDIM * 2);
  short* hlB    = (short*)alloc((size_t)NN * DDIM * 2);
  float* s_all  = (float*)alloc((size_t)3 * NN * 4);
  float* d_allb = (float*)alloc((size_t)3 * NN * 4);
  float* bias0  = (float*)alloc((size_t)NE * 4);
  float* bias1  = (float*)alloc((size_t)NE * 4);
  int* counts   = (int*)alloc((size_t)3 * NN * 4);
  int* offs_all = (int*)alloc((size_t)3 * (NN + 1) * 4);
  int* cur_all  = (int*)alloc((size_t)3 * (NN + 1) * 4);
  int* csrc_all = (int*)alloc((size_t)3 * NE * 4);
  int* ceid0    = (int*)alloc((size_t)NE * 4);
  short* wtd_hi = (short*)alloc((size_t)2048 * 128 * 2);
  short* wtd_lo = (short*)alloc((size_t)2048 * 128 * 2);
  short* wtt_hi = (short*)alloc((size_t)1280 * 128 * 2);
  short* wtt_lo = (short*)alloc((size_t)1280 * 128 * 2);
  short* wtg_hi = (short*)alloc((size_t)6 * 128 * 128 * 2);
  short* wtg_lo = (short*)alloc((size_t)6 * 128 * 128 * 2);

  // 0) weight prep (transpose + hi/lo split)
  prep_w<<<dim3((2048 * 128 + 255) / 256, 1), 256, 0, stream>>>(W_drug, wtd_hi, wtd_lo, 2048);
  prep_w<<<dim3((1280 * 128 + 255) / 256, 1), 256, 0, stream>>>(W_target, wtt_hi, wtt_lo, 1280);
  prep_w<<<dim3((128 * 128 + 255) / 256, 6), 256, 0, stream>>>(W_gat, wtg_hi, wtg_lo, 128);

  // 1) projections -> h hi/lo planes (one launch, LDS-staged, conflict-free pad)
  gemm_proj<<<1250, 256, 0, stream>>>(x_drug, wtd_hi, wtd_lo, b_drug,
                                      x_target, wtt_hi, wtt_lo, b_target, hhA, hlA);

  // 2) edge biases for both layers (one 256MB pass)
  edge_bias_kernel<<<NE / 4, 256, 0, stream>>>(edge_attr, a_edge, a_edge + DDIM,
                                               bias0, bias1);
  // 3) CSR build (3 relations, reused by both layers)
  hipMemsetAsync(counts, 0, (size_t)3 * NN * 4, stream);
  count3<<<dim3(170, 3), 256, 0, stream>>>(e_dd + NE, e_dt + NE, e_tt + NE, counts);
  scan3<<<3, 1024, 0, stream>>>(counts, offs_all, cur_all);
  fill3<<<dim3(170, 3), 256, 0, stream>>>(e_dd, e_dd + NE, e_dt, e_dt + NE,
                                          e_tt, e_tt + NE, cur_all, csrc_all, ceid0);

  // 4) two GAT layers
  // layer 0
  gemm_gat<<<dim3(1250, 3), 256, 0, stream>>>(hhA, hlA, wtg_hi, wtg_lo,
                                              a_src, a_dst, hp, s_all, d_allb);
  agg_all<<<NN / 4, 256, 0, stream>>>(offs_all, csrc_all, ceid0, bias0,
                                      s_all, d_allb, hp, nullptr, hhB, hlB, 0);
  // layer 1
  gemm_gat<<<dim3(1250, 3), 256, 0, stream>>>(hhB, hlB,
                                              wtg_hi + (size_t)3 * DDIM * DDIM,
                                              wtg_lo + (size_t)3 * DDIM * DDIM,
                                              a_src + 3 * DDIM, a_dst + 3 * DDIM,
                                              hp, s_all, d_allb);
  agg_all<<<NN / 4, 256, 0, stream>>>(offs_all, csrc_all, ceid0, bias1,
                                      s_all, d_allb, hp, out, nullptr, nullptr, 1);
}